// Round 3
// baseline (369.333 us; speedup 1.0000x reference)
//
#include <hip/hip_runtime.h>

// Problem constants (match reference)
#define BB    4
#define CC    32
#define HH    32
#define WW    1024
#define PATCH 21
#define DIL   2
#define RAD   10            // (PATCH-1)/2
#define PADW  20            // DIL*RAD : max displacement
#define CHUNK 4             // channels staged per LDS pass
#define LROW  (WW + 2*PADW) // 1064 floats per staged x2 row (16B-aligned stride)

// R3: ONE block per (b, pi, h) computing ALL 21 pj taps.
//  - kills the 3x redundant LDS staging + barriers of the 3-tap-group split
//  - window reads via a 12-float register ring: one ds_read_b128 every other
//    pj (each float4 enables 2 taps -> 8 FMAs per LDS read, zero addr math
//    in the FMA loop after unroll)
//  - acc[21][4]=84 VGPRs + ring 12 + x1 4 => ~115; __launch_bounds__(256,4)
//    caps at 128 VGPR = 4 blocks/CU (LDS 17KB*4=68KB fits), 16 waves/CU.
__global__ __launch_bounds__(256, 4)
void corr_kernel(const float* __restrict__ x1, const float* __restrict__ x2,
                 float* __restrict__ out) {
    __shared__ float sx2[CHUNK * LROW];   // 17 KB

    const int tid = threadIdx.x;
    const int h   = blockIdx.x;
    const int bp  = blockIdx.y;           // b*PATCH + pi
    const int b   = bp / PATCH;
    const int pi  = bp - b * PATCH;
    const int r2  = h + DIL * (pi - RAD); // x2 source row
    const int w4  = tid * 4;

    float* outp = out + (((size_t)(b * PATCH * PATCH + pi * PATCH)) * HH + h) * WW + w4;

    if (r2 < 0 || r2 >= HH) {
        // whole displacement row out of range -> zeros (leaky_relu(0)=0)
        float4 z = make_float4(0.f, 0.f, 0.f, 0.f);
#pragma unroll
        for (int j = 0; j < PATCH; j++)
            *(float4*)(outp + (size_t)j * HH * WW) = z;
        return;
    }

    const float* x1p = x1 + (((size_t)(b * CC) * HH + h) * WW) + w4;  // + c*HH*WW
    const float* x2p = x2 + (((size_t)(b * CC) * HH + r2) * WW);      // + c*HH*WW + u

    float acc[PATCH][4];
#pragma unroll
    for (int j = 0; j < PATCH; j++)
#pragma unroll
        for (int k = 0; k < 4; k++) acc[j][k] = 0.f;

    for (int cc = 0; cc < CC; cc += CHUNK) {
        __syncthreads();
        // Stage CHUNK x2 rows with +/-20 halo, zero-padded. All float4-granular.
        for (int idx = tid; idx < CHUNK * (LROW / 4); idx += 256) {
            int c  = idx / (LROW / 4);
            int i4 = idx - c * (LROW / 4);
            int u  = i4 * 4 - PADW;
            float4 v = make_float4(0.f, 0.f, 0.f, 0.f);
            if (u >= 0 && u <= WW - 4)
                v = *(const float4*)(x2p + (size_t)(cc + c) * HH * WW + u);
            *(float4*)&sx2[c * LROW + i4 * 4] = v;
        }
        __syncthreads();

#pragma unroll
        for (int c = 0; c < CHUNK; c++) {
            float4 av = *(const float4*)(x1p + (size_t)(cc + c) * HH * WW);
            const float a[4] = {av.x, av.y, av.z, av.w};

            // Window floats needed: sx2[c][w4 + i], i = 0..43 (pj window = 2j..2j+3).
            // Rolling 3x float4 ring: float i lives in ring[i % 12].
            const float* wb = &sx2[c * LROW + w4];
            float ring[12];
            *(float4*)&ring[0] = *(const float4*)(wb);          // f0 (floats 0..3)
#pragma unroll
            for (int j = 0; j < PATCH; j++) {
                if (j & 1) {
                    const int f = (j + 1) >> 1;                  // f1..f10
                    *(float4*)&ring[(f % 3) * 4] = *(const float4*)(wb + 4 * f);
                }
#pragma unroll
                for (int k = 0; k < 4; k++)
                    acc[j][k] = fmaf(a[k], ring[(2 * j + k) % 12], acc[j][k]);
            }
        }
    }

    const float inv_c = 1.0f / (float)CC;
#pragma unroll
    for (int j = 0; j < PATCH; j++) {
        float4 o;
        float* ov = (float*)&o;
#pragma unroll
        for (int k = 0; k < 4; k++) {
            float v = acc[j][k] * inv_c;
            ov[k] = v > 0.f ? v : 0.1f * v;
        }
        *(float4*)(outp + (size_t)j * HH * WW) = o;
    }
}

extern "C" void kernel_launch(void* const* d_in, const int* in_sizes, int n_in,
                              void* d_out, int out_size, void* d_ws, size_t ws_size,
                              hipStream_t stream) {
    const float* x1 = (const float*)d_in[0];
    const float* x2 = (const float*)d_in[1];
    float* out = (float*)d_out;

    dim3 grid(HH, BB * PATCH, 1);
    dim3 block(256, 1, 1);
    corr_kernel<<<grid, block, 0, stream>>>(x1, x2, out);
}

// Round 4
// 339.797 us; speedup vs baseline: 1.0869x; 1.0869x over previous
//
#include <hip/hip_runtime.h>

// Problem constants (match reference)
#define BB    4
#define CC    32
#define HH    32
#define WW    1024
#define PATCH 21
#define DIL   2
#define RAD   10            // (PATCH-1)/2
#define PADW  20            // DIL*RAD : max displacement
#define CHUNK 8             // channels staged per LDS pass (34 KB; 4 blocks/CU fits 160 KB)
#define LROW  (WW + 2*PADW) // 1064 floats per staged x2 row (16B-aligned stride)

// R4: one block per (b, pi, h), all 21 pj taps.
// R3 lesson: *(float4*)&reg_array[...] takes the address of a register array,
// defeats SROA -> scratch spill (VGPR=64, +87MB spill writes). Here acc[] and
// the r[] ring are float4 arrays touched ONLY with constant indices after
// unroll; LDS is read through a const float4* (memory, fine).
// Ring: window float i (i = 2j+k, 0..43) lives in r[(i/4)%3] component i%4.
// Even j: 2j%4==0 -> whole r[q]. Odd j: high half of r[q] + low half of r[q1].
__global__ __launch_bounds__(256, 4)
void corr_kernel(const float* __restrict__ x1, const float* __restrict__ x2,
                 float* __restrict__ out) {
    __shared__ float sx2[CHUNK * LROW];   // 34 KB

    const int tid = threadIdx.x;
    const int h   = blockIdx.x;
    const int bp  = blockIdx.y;           // b*PATCH + pi
    const int b   = bp / PATCH;
    const int pi  = bp - b * PATCH;
    const int r2  = h + DIL * (pi - RAD); // x2 source row
    const int w4  = tid * 4;

    float* outp = out + (((size_t)(b * PATCH * PATCH + pi * PATCH)) * HH + h) * WW + w4;

    if (r2 < 0 || r2 >= HH) {
        // whole displacement row out of range -> zeros (leaky_relu(0)=0)
        float4 z = make_float4(0.f, 0.f, 0.f, 0.f);
#pragma unroll
        for (int j = 0; j < PATCH; j++)
            *(float4*)(outp + (size_t)j * HH * WW) = z;
        return;
    }

    const float* x1p = x1 + (((size_t)(b * CC) * HH + h) * WW) + w4;  // + c*HH*WW
    const float* x2p = x2 + (((size_t)(b * CC) * HH + r2) * WW);      // + c*HH*WW + u

    float4 acc[PATCH];
#pragma unroll
    for (int j = 0; j < PATCH; j++) acc[j] = make_float4(0.f, 0.f, 0.f, 0.f);

    for (int cc = 0; cc < CC; cc += CHUNK) {
        __syncthreads();
        // Stage CHUNK x2 rows with +/-20 halo, zero-padded. All float4-granular.
        for (int idx = tid; idx < CHUNK * (LROW / 4); idx += 256) {
            int c  = idx / (LROW / 4);
            int i4 = idx - c * (LROW / 4);
            int u  = i4 * 4 - PADW;
            float4 v = make_float4(0.f, 0.f, 0.f, 0.f);
            if (u >= 0 && u <= WW - 4)
                v = *(const float4*)(x2p + (size_t)(cc + c) * HH * WW + u);
            *(float4*)&sx2[c * LROW + i4 * 4] = v;
        }
        __syncthreads();

#pragma unroll
        for (int c = 0; c < CHUNK; c++) {
            const float4 a = *(const float4*)(x1p + (size_t)(cc + c) * HH * WW);
            const float4* wb4 = (const float4*)&sx2[c * LROW + w4];  // 16B aligned

            float4 r[3];
            r[0] = wb4[0];
#pragma unroll
            for (int j = 0; j < PATCH; j++) {
                if (j & 1) {
                    const int f = (j + 1) >> 1;      // f1..f10, slot (f%3)
                    r[f % 3] = wb4[f];
                }
                const int s  = 2 * j;
                const int q  = (s >> 2) % 3;
                const int q1 = (q + 1) % 3;
                if ((s & 3) == 0) {
                    acc[j].x = fmaf(a.x, r[q].x, acc[j].x);
                    acc[j].y = fmaf(a.y, r[q].y, acc[j].y);
                    acc[j].z = fmaf(a.z, r[q].z, acc[j].z);
                    acc[j].w = fmaf(a.w, r[q].w, acc[j].w);
                } else {
                    acc[j].x = fmaf(a.x, r[q].z,  acc[j].x);
                    acc[j].y = fmaf(a.y, r[q].w,  acc[j].y);
                    acc[j].z = fmaf(a.z, r[q1].x, acc[j].z);
                    acc[j].w = fmaf(a.w, r[q1].y, acc[j].w);
                }
            }
        }
    }

    const float inv_c = 1.0f / (float)CC;
#pragma unroll
    for (int j = 0; j < PATCH; j++) {
        float4 o;
        o.x = acc[j].x * inv_c; o.x = o.x > 0.f ? o.x : 0.1f * o.x;
        o.y = acc[j].y * inv_c; o.y = o.y > 0.f ? o.y : 0.1f * o.y;
        o.z = acc[j].z * inv_c; o.z = o.z > 0.f ? o.z : 0.1f * o.z;
        o.w = acc[j].w * inv_c; o.w = o.w > 0.f ? o.w : 0.1f * o.w;
        *(float4*)(outp + (size_t)j * HH * WW) = o;
    }
}

extern "C" void kernel_launch(void* const* d_in, const int* in_sizes, int n_in,
                              void* d_out, int out_size, void* d_ws, size_t ws_size,
                              hipStream_t stream) {
    const float* x1 = (const float*)d_in[0];
    const float* x2 = (const float*)d_in[1];
    float* out = (float*)d_out;

    dim3 grid(HH, BB * PATCH, 1);
    dim3 block(256, 1, 1);
    corr_kernel<<<grid, block, 0, stream>>>(x1, x2, out);
}